// Round 4
// baseline (343.436 us; speedup 1.0000x reference)
//
#include <hip/hip_runtime.h>

// GeneralConvNd (7x7, Cin=1, Cout=64, 'same') as implicit GEMM, no-LDS version.
// out[b,h,w,c] = sum_{ky,kx} x[b,h+ky-3,w+kx-3] * W[ky*7+kx,c] + bias[c]
//
// Tap re-index (k-permutation cancels between A and B frags): t = ky*8+kx,
// t in [0,64); kx==7 or ky==7 are dummy taps with W=0 (x value finite garbage).
// Per lane (lq=lane>>4, lr=lane&15), frag element (ch,j): ky=ch*4+lq, kx=j
// -> each chunk's 8 x-values are 8 CONSECUTIVE floats of one row: 2x16B loads.
//
// MFMA operands swapped vs classic: A = W^T (chan x k), B = patches (k x px),
// D[chan][px]: chan = g*16 + lq*4 + reg, px = w0 + lr  ->  per-lane acc is 4
// consecutive channels at one pixel => 4x global_store_dwordx4 per wave-tile.
// W-frags (32 VGPR) + bias (16 VGPR) loaded once per wave, amortized over 9
// grid-strided tiles. No LDS, no barriers.
//
// R4 change (single A/B): output stores are NONTEMPORAL (`nt`) — the 302 MB
// result stream is never re-read; keeping it out of temporal L2 residency
// avoids dirty-eviction churn against the (tiny, reused) x read stream.
// Kernel is write-BW-bound: floor = 302 MB / ~6.2 TB/s ~= 49 us.

#define HH 384
#define WW 384
#define BB 8
#define CC 64
#define TPW 16                         // pixels per wave-tile
#define TROW (WW / TPW)                // 24 tiles per image row
#define NTILES (BB * HH * TROW)        // 73728
#define NBLOCKS 2048
#define WPB 4
#define NWAVES (NBLOCKS * WPB)         // 8192
#define TPWAVE (NTILES / NWAVES)       // 9 exactly

typedef __attribute__((ext_vector_type(8))) __bf16 bf16x8;
typedef __attribute__((ext_vector_type(4))) float f32x4;

__global__ __launch_bounds__(256)
void conv7_mfma_nt(const float* __restrict__ xg, const float* __restrict__ wg,
                   const float* __restrict__ bg, float* __restrict__ out)
{
    const int tid  = threadIdx.x;
    const int lane = tid & 63;
    const int wv   = tid >> 6;
    const int lq   = lane >> 4;   // 0..3
    const int lr   = lane & 15;   // 0..15

    // ---- A-operand (W^T) fragments + bias: once per wave ----
    bf16x8 wfr[2][4];
#pragma unroll
    for (int ch = 0; ch < 2; ++ch)
#pragma unroll
        for (int g = 0; g < 4; ++g) {
            bf16x8 f;
#pragma unroll
            for (int j = 0; j < 8; ++j) {
                const int ky = ch * 4 + lq;          // 0..7
                const int kx = j;                    // 0..7
                f[j] = (ky < 7 && kx < 7) ? (__bf16)wg[(ky * 7 + kx) * CC + g * 16 + lr]
                                          : (__bf16)0.f;
            }
            wfr[ch][g] = f;
        }
    f32x4 biasf[4];
#pragma unroll
    for (int g = 0; g < 4; ++g)
        biasf[g] = *(const f32x4*)(bg + g * 16 + lq * 4);   // 16B-aligned

    const int gw = blockIdx.x * WPB + wv;

    for (int it = 0; it < TPWAVE; ++it) {
        const int tile = gw * TPWAVE + it;           // consecutive -> L1 reuse of x
        const int tw = tile % TROW;
        const int rh = tile / TROW;
        const int h  = rh % HH;
        const int b  = rh / HH;
        const int w0 = tw * TPW;

        // ---- B-operand (patches) fragments, straight from global ----
        bf16x8 xf[2];
        const bool interior = (h >= 3) & (h <= HH - 5) & (w0 != 0) & (w0 != WW - TPW);
        if (interior) {
            const float* p0 = xg + ((size_t)b * HH + (h - 3)) * WW + (w0 - 3 + lr);
#pragma unroll
            for (int ch = 0; ch < 2; ++ch) {
                float v[8];
                __builtin_memcpy(v, p0 + (size_t)(ch * 4 + lq) * WW, 32);
                bf16x8 f;
#pragma unroll
                for (int j = 0; j < 8; ++j) f[j] = (__bf16)v[j];
                xf[ch] = f;
            }
        } else {
#pragma unroll
            for (int ch = 0; ch < 2; ++ch) {
                const int r  = h - 3 + ch * 4 + lq;
                const int rc = r < 0 ? 0 : (r > HH - 1 ? HH - 1 : r);
                const bool rok = (r >= 0) & (r < HH);
                const float* prow = xg + ((size_t)b * HH + rc) * WW;
                bf16x8 f;
#pragma unroll
                for (int j = 0; j < 8; ++j) {
                    const int c  = w0 - 3 + lr + j;
                    const int cc = c < 0 ? 0 : (c > WW - 1 ? WW - 1 : c);
                    float v = prow[cc];                       // always in-bounds
                    v = (rok & (c >= 0) & (c < WW)) ? v : 0.f; // cndmask, no branch
                    f[j] = (__bf16)v;
                }
                xf[ch] = f;
            }
        }

        f32x4 acc[4];
#pragma unroll
        for (int g = 0; g < 4; ++g) acc[g] = biasf[g];
#pragma unroll
        for (int ch = 0; ch < 2; ++ch)
#pragma unroll
            for (int g = 0; g < 4; ++g)
                acc[g] = __builtin_amdgcn_mfma_f32_16x16x32_bf16(
                    wfr[ch][g], xf[ch], acc[g], 0, 0, 0);

        // ---- store: 4 consecutive chans per lane -> dwordx4, NONTEMPORAL ----
        float* op = out + (((size_t)b * HH + h) * WW + w0 + lr) * CC + lq * 4;
#pragma unroll
        for (int g = 0; g < 4; ++g)
            __builtin_nontemporal_store(acc[g], (f32x4*)(op + g * 16));
    }
}

extern "C" void kernel_launch(void* const* d_in, const int* in_sizes, int n_in,
                              void* d_out, int out_size, void* d_ws, size_t ws_size,
                              hipStream_t stream) {
    const float* x = (const float*)d_in[0];   // [8,384,384] f32
    const float* w = (const float*)d_in[1];   // [49,64] f32
    const float* b = (const float*)d_in[2];   // [64] f32
    float* out = (float*)d_out;               // [8,384,384,64] f32
    (void)in_sizes; (void)n_in; (void)out_size; (void)d_ws; (void)ws_size;
    conv7_mfma_nt<<<NBLOCKS, 256, 0, stream>>>(x, w, b, out);
}

// Round 5
// 316.739 us; speedup vs baseline: 1.0843x; 1.0843x over previous
//
#include <hip/hip_runtime.h>

// GeneralConvNd (7x7, Cin=1, Cout=64, 'same') as implicit GEMM via bf16 MFMA.
// out[b,h,w,c] = sum_{ky,kx} x[b,h+ky-3,w+kx-3] * W[ky*7+kx,c] + bias[c]
//
// Front-end (unchanged from R3): tap re-index t=ky*8+kx with zero-weight dummy
// taps; per lane the 8 frag elems per K-chunk are 8 consecutive floats of one
// x row -> 2x16B global loads (x is L2-resident). A=W^T frags + bias in regs,
// amortized over 9 grid-strided tiles. No barriers.
//
// R5 change (single A/B vs R3): STORE TRANSPOSE. R2/R3 both emitted 64B-granule
// stores (half a 128B L2 line) and both landed at ~90us = 302MB at 3.4TB/s --
// exactly half the fill's 6.3TB/s, consistent with read-for-ownership doubling
// HBM traffic on partial-line write misses. Fix: per-wave-private LDS bounce
// ([16][68] f32, 272B padded rows, bank-uniform) to transpose the 4KB tile, so
// each of the 4 global_store_dwordx4 writes 64 lanes x 16B = 1KB CONTIGUOUS
// (full lines only). Extra ~8 LDS ops/tile ~= 3-4us aggregate.

#define HH 384
#define WW 384
#define BB 8
#define CC 64
#define TPW 16                         // pixels per wave-tile
#define TROW (WW / TPW)                // 24 tiles per image row
#define NTILES (BB * HH * TROW)        // 73728
#define NBLOCKS 2048
#define WPB 4
#define NWAVES (NBLOCKS * WPB)         // 8192
#define TPWAVE (NTILES / NWAVES)       // 9 exactly

typedef __attribute__((ext_vector_type(8))) __bf16 bf16x8;
typedef __attribute__((ext_vector_type(4))) float f32x4;

__global__ __launch_bounds__(256)
void conv7_mfma_st(const float* __restrict__ xg, const float* __restrict__ wg,
                   const float* __restrict__ bg, float* __restrict__ out)
{
    __shared__ float lt[WPB][16][68];  // per-wave 4KB tile, 272B rows (bank-spread)

    const int tid  = threadIdx.x;
    const int lane = tid & 63;
    const int wv   = tid >> 6;
    const int lq   = lane >> 4;   // 0..3
    const int lr   = lane & 15;   // 0..15

    // ---- A-operand (W^T) fragments + bias: once per wave ----
    bf16x8 wfr[2][4];
#pragma unroll
    for (int ch = 0; ch < 2; ++ch)
#pragma unroll
        for (int g = 0; g < 4; ++g) {
            bf16x8 f;
#pragma unroll
            for (int j = 0; j < 8; ++j) {
                const int ky = ch * 4 + lq;          // 0..7
                const int kx = j;                    // 0..7
                f[j] = (ky < 7 && kx < 7) ? (__bf16)wg[(ky * 7 + kx) * CC + g * 16 + lr]
                                          : (__bf16)0.f;
            }
            wfr[ch][g] = f;
        }
    f32x4 biasf[4];
#pragma unroll
    for (int g = 0; g < 4; ++g)
        biasf[g] = *(const f32x4*)(bg + g * 16 + lq * 4);   // 16B-aligned

    const int gw = blockIdx.x * WPB + wv;

    for (int it = 0; it < TPWAVE; ++it) {
        const int tile = gw * TPWAVE + it;           // consecutive -> L1/L2 reuse of x
        const int tw = tile % TROW;
        const int rh = tile / TROW;
        const int h  = rh % HH;
        const int b  = rh / HH;
        const int w0 = tw * TPW;

        // ---- B-operand (patches) fragments, straight from global ----
        bf16x8 xf[2];
        const bool interior = (h >= 3) & (h <= HH - 5) & (w0 != 0) & (w0 != WW - TPW);
        if (interior) {
            const float* p0 = xg + ((size_t)b * HH + (h - 3)) * WW + (w0 - 3 + lr);
#pragma unroll
            for (int ch = 0; ch < 2; ++ch) {
                float v[8];
                __builtin_memcpy(v, p0 + (size_t)(ch * 4 + lq) * WW, 32);
                bf16x8 f;
#pragma unroll
                for (int j = 0; j < 8; ++j) f[j] = (__bf16)v[j];
                xf[ch] = f;
            }
        } else {
#pragma unroll
            for (int ch = 0; ch < 2; ++ch) {
                const int r  = h - 3 + ch * 4 + lq;
                const int rc = r < 0 ? 0 : (r > HH - 1 ? HH - 1 : r);
                const bool rok = (r >= 0) & (r < HH);
                const float* prow = xg + ((size_t)b * HH + rc) * WW;
                bf16x8 f;
#pragma unroll
                for (int j = 0; j < 8; ++j) {
                    const int c  = w0 - 3 + lr + j;
                    const int cc = c < 0 ? 0 : (c > WW - 1 ? WW - 1 : c);
                    float v = prow[cc];                        // always in-bounds
                    v = (rok & (c >= 0) & (c < WW)) ? v : 0.f; // cndmask, no branch
                    f[j] = (__bf16)v;
                }
                xf[ch] = f;
            }
        }

        f32x4 acc[4];
#pragma unroll
        for (int g = 0; g < 4; ++g) acc[g] = biasf[g];
#pragma unroll
        for (int ch = 0; ch < 2; ++ch)
#pragma unroll
            for (int g = 0; g < 4; ++g)
                acc[g] = __builtin_amdgcn_mfma_f32_16x16x32_bf16(
                    wfr[ch][g], xf[ch], acc[g], 0, 0, 0);

        // ---- store transpose via per-wave-private LDS (no barrier) ----
        // write: lane holds (px=lr, chans g*16+lq*4+0..3) -> lt[wv][px][chan]
        float* lw = &lt[wv][lr][0];
#pragma unroll
        for (int g = 0; g < 4; ++g)
            *(f32x4*)(lw + g * 16 + lq * 4) = acc[g];   // ds_write_b128
        // read back linear: float idx f = g*256 + lane*4 of the 4KB tile
        //   px = 4g + (lane>>4), chan = (lane&15)*4
        const float* lrd = &lt[wv][0][0];
        f32x4 ov[4];
#pragma unroll
        for (int g = 0; g < 4; ++g)
            ov[g] = *(const f32x4*)(lrd + (size_t)(4 * g + lq) * 68 + lr * 4);
        // store: 4 x fully-contiguous 1KB (64 lanes x 16B) per wave-tile
        float* op = out + (((size_t)b * HH + h) * WW + w0) * CC;
#pragma unroll
        for (int g = 0; g < 4; ++g)
            *(f32x4*)(op + g * 256 + lane * 4) = ov[g];
    }
}

extern "C" void kernel_launch(void* const* d_in, const int* in_sizes, int n_in,
                              void* d_out, int out_size, void* d_ws, size_t ws_size,
                              hipStream_t stream) {
    const float* x = (const float*)d_in[0];   // [8,384,384] f32
    const float* w = (const float*)d_in[1];   // [49,64] f32
    const float* b = (const float*)d_in[2];   // [64] f32
    float* out = (float*)d_out;               // [8,384,384,64] f32
    (void)in_sizes; (void)n_in; (void)out_size; (void)d_ws; (void)ws_size;
    conv7_mfma_st<<<NBLOCKS, 256, 0, stream>>>(x, w, b, out);
}

// Round 6
// 316.242 us; speedup vs baseline: 1.0860x; 1.0016x over previous
//
#include <hip/hip_runtime.h>

// GeneralConvNd (7x7, Cin=1, Cout=64, 'same') as implicit GEMM via bf16 MFMA.
// out[b,h,w,c] = sum_{ky,kx} x[b,h+ky-3,w+kx-3] * W[ky*7+kx,c] + bias[c]
//
// R6: wave-PAIR structure for occupancy. Each 512-thread block has 4 pairs;
// a pair shares one 16-px tile stream, each wave does 32 of the 64 chans
// (cb = (wv&1)*32). Register cut: wfr 32->16, acc 16->8, biasf 16->4 (bias
// added POST-transpose, indexed by store lane), ov 16->8 => ~60-70 VGPR ->
// 7-8 waves/SIMD (was ~4). More waves = more outstanding stores to cover the
// per-tile load->MFMA->LDS chains; kernel is write-BW-bound (302 MB floor
// ~49 us; R5 measured ~62 us at 4.9 TB/s vs fill 6.2 TB/s).
//
// Store path (R5's win, kept): per-wave-private LDS bounce ([16][36] f32,
// 144B rows, 16B-aligned) transposes D[chan][px] -> memory order; each store
// inst = 64 lanes x 16B = 8 FULL 128B lines (no partial-line RFO).
// Tap re-index t=ky*8+kx with zero-weight dummy taps (k-permutation cancels
// between A and B frags); per lane the 8 frag elems per K-chunk are 8
// consecutive floats of one x row -> 2x16B global loads (x is L2-resident).

#define HH 384
#define WW 384
#define BB 8
#define CC 64
#define TPW 16                         // pixels per pair-tile
#define TROW (WW / TPW)                // 24 tiles per image row
#define NTILES (BB * HH * TROW)        // 73728
#define NBLOCKS 2048
#define PPB 4                          // pairs per block (8 waves)
#define NPAIRS (NBLOCKS * PPB)         // 8192
#define TPPAIR (NTILES / NPAIRS)       // 9 exactly

typedef __attribute__((ext_vector_type(8))) __bf16 bf16x8;
typedef __attribute__((ext_vector_type(4))) float f32x4;

__global__ __launch_bounds__(512)
void conv7_mfma_w8(const float* __restrict__ xg, const float* __restrict__ wg,
                   const float* __restrict__ bg, float* __restrict__ out)
{
    __shared__ float lt[8][16][36];    // per-wave 2KB tile, 144B rows

    const int tid  = threadIdx.x;
    const int lane = tid & 63;
    const int wv   = tid >> 6;    // 0..7
    const int lq   = lane >> 4;   // 0..3
    const int lr   = lane & 15;   // 0..15
    const int pr   = wv >> 1;     // pair 0..3
    const int cb   = (wv & 1) * 32;   // this wave's channel base

    // ---- A-operand (W^T) fragments: once per wave (16 VGPR) ----
    bf16x8 wfr[2][2];
#pragma unroll
    for (int ch = 0; ch < 2; ++ch)
#pragma unroll
        for (int g = 0; g < 2; ++g) {
            bf16x8 f;
#pragma unroll
            for (int j = 0; j < 8; ++j) {
                const int ky = ch * 4 + lq;          // 0..7
                const int kx = j;                    // 0..7
                f[j] = (ky < 7 && kx < 7)
                     ? (__bf16)wg[(ky * 7 + kx) * CC + cb + g * 16 + lr]
                     : (__bf16)0.f;
            }
            wfr[ch][g] = f;
        }
    // bias in STORE layout: chan = cb + (lane&7)*4 .. +3 (one f32x4)
    const f32x4 biast = *(const f32x4*)(bg + cb + (lane & 7) * 4);

    const int gp = blockIdx.x * PPB + pr;

    for (int it = 0; it < TPPAIR; ++it) {
        const int tile = gp * TPPAIR + it;           // consecutive -> L1/L2 reuse
        const int tw = tile % TROW;
        const int rh = tile / TROW;
        const int h  = rh % HH;
        const int b  = rh / HH;
        const int w0 = tw * TPW;

        // ---- B-operand (patches) fragments, straight from global ----
        bf16x8 xf[2];
        const bool interior = (h >= 3) & (h <= HH - 5) & (w0 != 0) & (w0 != WW - TPW);
        if (interior) {
            const float* p0 = xg + ((size_t)b * HH + (h - 3)) * WW + (w0 - 3 + lr);
#pragma unroll
            for (int ch = 0; ch < 2; ++ch) {
                float v[8];
                __builtin_memcpy(v, p0 + (size_t)(ch * 4 + lq) * WW, 32);
                bf16x8 f;
#pragma unroll
                for (int j = 0; j < 8; ++j) f[j] = (__bf16)v[j];
                xf[ch] = f;
            }
        } else {
#pragma unroll
            for (int ch = 0; ch < 2; ++ch) {
                const int r  = h - 3 + ch * 4 + lq;
                const int rc = r < 0 ? 0 : (r > HH - 1 ? HH - 1 : r);
                const bool rok = (r >= 0) & (r < HH);
                const float* prow = xg + ((size_t)b * HH + rc) * WW;
                bf16x8 f;
#pragma unroll
                for (int j = 0; j < 8; ++j) {
                    const int c  = w0 - 3 + lr + j;
                    const int cc = c < 0 ? 0 : (c > WW - 1 ? WW - 1 : c);
                    float v = prow[cc];                        // always in-bounds
                    v = (rok & (c >= 0) & (c < WW)) ? v : 0.f; // cndmask, no branch
                    f[j] = (__bf16)v;
                }
                xf[ch] = f;
            }
        }

        f32x4 acc[2] = {(f32x4){0.f,0.f,0.f,0.f}, (f32x4){0.f,0.f,0.f,0.f}};
#pragma unroll
        for (int ch = 0; ch < 2; ++ch)
#pragma unroll
            for (int g = 0; g < 2; ++g)
                acc[g] = __builtin_amdgcn_mfma_f32_16x16x32_bf16(
                    wfr[ch][g], xf[ch], acc[g], 0, 0, 0);

        // ---- store transpose via per-wave-private LDS (no barrier) ----
        // D layout: chan = cb + g*16 + lq*4 + reg, px = lr
        float* lw = &lt[wv][lr][0];
#pragma unroll
        for (int g = 0; g < 2; ++g)
            *(f32x4*)(lw + g * 16 + lq * 4) = acc[g];   // ds_write_b128
        // read in memory order: store g covers px [g*8, g*8+8) x 32 chans
        f32x4 ov[2];
#pragma unroll
        for (int g = 0; g < 2; ++g) {
            ov[g] = *(const f32x4*)(&lt[wv][g * 8 + (lane >> 3)][(lane & 7) * 4]);
            ov[g] += biast;
        }
        // each store: 64 lanes x 16B = 8 full 128B lines (256B stride)
        float* op = out + (((size_t)b * HH + h) * WW + w0) * CC + cb;
#pragma unroll
        for (int g = 0; g < 2; ++g)
            *(f32x4*)(op + (size_t)(g * 8 + (lane >> 3)) * CC + (lane & 7) * 4) = ov[g];
    }
}

extern "C" void kernel_launch(void* const* d_in, const int* in_sizes, int n_in,
                              void* d_out, int out_size, void* d_ws, size_t ws_size,
                              hipStream_t stream) {
    const float* x = (const float*)d_in[0];   // [8,384,384] f32
    const float* w = (const float*)d_in[1];   // [49,64] f32
    const float* b = (const float*)d_in[2];   // [64] f32
    float* out = (float*)d_out;               // [8,384,384,64] f32
    (void)in_sizes; (void)n_in; (void)out_size; (void)d_ws; (void)ws_size;
    conv7_mfma_w8<<<NBLOCKS, 512, 0, stream>>>(x, w, b, out);
}

// Round 8
// 310.773 us; speedup vs baseline: 1.1051x; 1.0176x over previous
//
#include <hip/hip_runtime.h>

// GeneralConvNd (7x7, Cin=1, Cout=64, 'same') as implicit GEMM via bf16 MFMA.
// out[b,h,w,c] = sum_{ky,kx} x[b,h+ky-3,w+kx-3] * W[ky*7+kx,c] + bias[c]
//
// R7 (resubmit; R7 bench was a broker timeout, no data): R6 + NONTEMPORAL on
// the (now full-line) output stores. R4's NT regression was confounded by
// 64B-granule stores (partial 128B lines + NT = fine-grain DRAM write-modify).
// R6 stores compose full 128B lines per instruction (8 lanes x 16B per line),
// so NT now only skips the L2 allocate/evict round-trip for 302 MB of
// never-re-read data, protecting the x read set.
//
// Structure (R6, kept): 512-thr blocks = 4 wave-pairs; each pair owns a 16-px
// tile stream (9 grid-strided consecutive tiles), each wave 32 of 64 chans.
// W^T frags (16 VGPR) + bias (4 VGPR, store-layout) in regs. Patches built
// straight from global (x is L2-resident): tap re-index t=ky*8+kx with
// zero-weight dummy taps; per lane, 8 frag elems per K-chunk = 8 consecutive
// floats of one x row -> 2x16B loads. 4x mfma_f32_16x16x32_bf16.
// Store transpose via per-wave-private LDS ([16][36] f32, no barrier), then
// 2 stores/tile, each 64 lanes x 16B = 8 full 128B lines. Write-BW-bound:
// floor ~49us write + ~6us cold-x; R6 measured ~63us.

#define HH 384
#define WW 384
#define BB 8
#define CC 64
#define TPW 16                         // pixels per pair-tile
#define TROW (WW / TPW)                // 24 tiles per image row
#define NTILES (BB * HH * TROW)        // 73728
#define NBLOCKS 2048
#define PPB 4                          // pairs per block (8 waves)
#define NPAIRS (NBLOCKS * PPB)         // 8192
#define TPPAIR (NTILES / NPAIRS)       // 9 exactly

typedef __attribute__((ext_vector_type(8))) __bf16 bf16x8;
typedef __attribute__((ext_vector_type(4))) float f32x4;

__global__ __launch_bounds__(512)
void conv7_mfma_w8nt(const float* __restrict__ xg, const float* __restrict__ wg,
                     const float* __restrict__ bg, float* __restrict__ out)
{
    __shared__ float lt[8][16][36];    // per-wave 2KB tile, 144B rows

    const int tid  = threadIdx.x;
    const int lane = tid & 63;
    const int wv   = tid >> 6;    // 0..7
    const int lq   = lane >> 4;   // 0..3
    const int lr   = lane & 15;   // 0..15
    const int pr   = wv >> 1;     // pair 0..3
    const int cb   = (wv & 1) * 32;   // this wave's channel base

    // ---- A-operand (W^T) fragments: once per wave (16 VGPR) ----
    bf16x8 wfr[2][2];
#pragma unroll
    for (int ch = 0; ch < 2; ++ch)
#pragma unroll
        for (int g = 0; g < 2; ++g) {
            bf16x8 f;
#pragma unroll
            for (int j = 0; j < 8; ++j) {
                const int ky = ch * 4 + lq;          // 0..7
                const int kx = j;                    // 0..7
                f[j] = (ky < 7 && kx < 7)
                     ? (__bf16)wg[(ky * 7 + kx) * CC + cb + g * 16 + lr]
                     : (__bf16)0.f;
            }
            wfr[ch][g] = f;
        }
    // bias in STORE layout: chan = cb + (lane&7)*4 .. +3 (one f32x4)
    const f32x4 biast = *(const f32x4*)(bg + cb + (lane & 7) * 4);

    const int gp = blockIdx.x * PPB + pr;

    for (int it = 0; it < TPPAIR; ++it) {
        const int tile = gp * TPPAIR + it;           // consecutive -> L1/L2 reuse
        const int tw = tile % TROW;
        const int rh = tile / TROW;
        const int h  = rh % HH;
        const int b  = rh / HH;
        const int w0 = tw * TPW;

        // ---- B-operand (patches) fragments, straight from global ----
        bf16x8 xf[2];
        const bool interior = (h >= 3) & (h <= HH - 5) & (w0 != 0) & (w0 != WW - TPW);
        if (interior) {
            const float* p0 = xg + ((size_t)b * HH + (h - 3)) * WW + (w0 - 3 + lr);
#pragma unroll
            for (int ch = 0; ch < 2; ++ch) {
                float v[8];
                __builtin_memcpy(v, p0 + (size_t)(ch * 4 + lq) * WW, 32);
                bf16x8 f;
#pragma unroll
                for (int j = 0; j < 8; ++j) f[j] = (__bf16)v[j];
                xf[ch] = f;
            }
        } else {
#pragma unroll
            for (int ch = 0; ch < 2; ++ch) {
                const int r  = h - 3 + ch * 4 + lq;
                const int rc = r < 0 ? 0 : (r > HH - 1 ? HH - 1 : r);
                const bool rok = (r >= 0) & (r < HH);
                const float* prow = xg + ((size_t)b * HH + rc) * WW;
                bf16x8 f;
#pragma unroll
                for (int j = 0; j < 8; ++j) {
                    const int c  = w0 - 3 + lr + j;
                    const int cc = c < 0 ? 0 : (c > WW - 1 ? WW - 1 : c);
                    float v = prow[cc];                        // always in-bounds
                    v = (rok & (c >= 0) & (c < WW)) ? v : 0.f; // cndmask, no branch
                    f[j] = (__bf16)v;
                }
                xf[ch] = f;
            }
        }

        f32x4 acc[2] = {(f32x4){0.f,0.f,0.f,0.f}, (f32x4){0.f,0.f,0.f,0.f}};
#pragma unroll
        for (int ch = 0; ch < 2; ++ch)
#pragma unroll
            for (int g = 0; g < 2; ++g)
                acc[g] = __builtin_amdgcn_mfma_f32_16x16x32_bf16(
                    wfr[ch][g], xf[ch], acc[g], 0, 0, 0);

        // ---- store transpose via per-wave-private LDS (no barrier) ----
        // D layout: chan = cb + g*16 + lq*4 + reg, px = lr
        float* lw = &lt[wv][lr][0];
#pragma unroll
        for (int g = 0; g < 2; ++g)
            *(f32x4*)(lw + g * 16 + lq * 4) = acc[g];   // ds_write_b128
        // read in memory order: store g covers px [g*8, g*8+8) x 32 chans
        f32x4 ov[2];
#pragma unroll
        for (int g = 0; g < 2; ++g) {
            ov[g] = *(const f32x4*)(&lt[wv][g * 8 + (lane >> 3)][(lane & 7) * 4]);
            ov[g] += biast;
        }
        // each store: 64 lanes x 16B = 8 full 128B lines (256B stride), NT
        float* op = out + (((size_t)b * HH + h) * WW + w0) * CC + cb;
#pragma unroll
        for (int g = 0; g < 2; ++g)
            __builtin_nontemporal_store(
                ov[g], (f32x4*)(op + (size_t)(g * 8 + (lane >> 3)) * CC + (lane & 7) * 4));
    }
}

extern "C" void kernel_launch(void* const* d_in, const int* in_sizes, int n_in,
                              void* d_out, int out_size, void* d_ws, size_t ws_size,
                              hipStream_t stream) {
    const float* x = (const float*)d_in[0];   // [8,384,384] f32
    const float* w = (const float*)d_in[1];   // [49,64] f32
    const float* b = (const float*)d_in[2];   // [64] f32
    float* out = (float*)d_out;               // [8,384,384,64] f32
    (void)in_sizes; (void)n_in; (void)out_size; (void)d_ws; (void)ws_size;
    conv7_mfma_w8nt<<<NBLOCKS, 512, 0, stream>>>(x, w, b, out);
}